// Round 2
// baseline (3855.300 us; speedup 1.0000x reference)
//
#include <hip/hip_runtime.h>
#include <math.h>

#define B_ROWS 1024
#define D_IN   2048
#define D_HID  4096
#define D_UP   4096
#define NH     8
#define HS     512
#define LN_EPS 1e-5f

__device__ __forceinline__ float sigmoidf_(float x) { return 1.0f / (1.0f + expf(-x)); }
__device__ __forceinline__ float siluf_(float x)    { return x / (1.0f + expf(-x)); }

// ---------------------------------------------------------------------------
// Generic f32 GEMM: C = alpha*(A @ W + bias) [+ resid]
// A: (M,K) lda, W: (K,N) ldb row-major, C: (M,N) ldc. Batched via blockIdx.z
// with element strides aB/wB/bB/cB. Tiles: 64x64, BK=16, 256 thr, 4x4/thread.
// All dims assumed divisible by tile sizes (true for this problem).
// ---------------------------------------------------------------------------
__global__ __launch_bounds__(256) void sgemm_kernel(
    const float* __restrict__ A, const float* __restrict__ W,
    const float* __restrict__ bias, const float* __restrict__ resid,
    float* __restrict__ C,
    int K, int lda, int ldb, int ldc,
    long aB, long wB, long bB, long cB, float alpha)
{
    const int bz = blockIdx.z;
    A += (long)bz * aB;
    W += (long)bz * wB;
    bias += (long)bz * bB;
    C += (long)bz * cB;

    __shared__ float As[16][64];   // As[k][m]
    __shared__ float Bs[16][64];   // Bs[k][n]

    const int t  = threadIdx.x;
    const int tx = t & 15;         // n-subtile
    const int ty = t >> 4;         // m-subtile
    const long rowBase = (long)blockIdx.y * 64;
    const int  colBase = blockIdx.x * 64;

    // A loader: thread t loads 4 consecutive k's of one row
    const int aRow = t >> 2;             // 0..63
    const int aK0  = (t & 3) << 2;       // 0,4,8,12
    // B loader: thread t loads 4 consecutive n's of one k-row
    const int bK   = t >> 4;             // 0..15
    const int bN0  = (t & 15) << 2;      // 0..60

    const float* Aptr = A + (rowBase + aRow) * lda + aK0;
    const float* Wptr = W + (long)bK * ldb + colBase + bN0;

    float acc[4][4] = {};

    for (int kb = 0; kb < K; kb += 16) {
        const float4 av = *reinterpret_cast<const float4*>(Aptr + kb);
        const float4 bv = *reinterpret_cast<const float4*>(Wptr + (long)kb * ldb);
        As[aK0 + 0][aRow] = av.x;
        As[aK0 + 1][aRow] = av.y;
        As[aK0 + 2][aRow] = av.z;
        As[aK0 + 3][aRow] = av.w;
        *reinterpret_cast<float4*>(&Bs[bK][bN0]) = bv;
        __syncthreads();
#pragma unroll
        for (int kk = 0; kk < 16; ++kk) {
            const float a0 = As[kk][ty * 4 + 0];
            const float a1 = As[kk][ty * 4 + 1];
            const float a2 = As[kk][ty * 4 + 2];
            const float a3 = As[kk][ty * 4 + 3];
            const float b0 = Bs[kk][tx * 4 + 0];
            const float b1 = Bs[kk][tx * 4 + 1];
            const float b2 = Bs[kk][tx * 4 + 2];
            const float b3 = Bs[kk][tx * 4 + 3];
            acc[0][0] += a0 * b0; acc[0][1] += a0 * b1; acc[0][2] += a0 * b2; acc[0][3] += a0 * b3;
            acc[1][0] += a1 * b0; acc[1][1] += a1 * b1; acc[1][2] += a1 * b2; acc[1][3] += a1 * b3;
            acc[2][0] += a2 * b0; acc[2][1] += a2 * b1; acc[2][2] += a2 * b2; acc[2][3] += a2 * b3;
            acc[3][0] += a3 * b0; acc[3][1] += a3 * b1; acc[3][2] += a3 * b2; acc[3][3] += a3 * b3;
        }
        __syncthreads();
    }

    const int col = colBase + tx * 4;
#pragma unroll
    for (int i = 0; i < 4; ++i) {
        const long row = rowBase + ty * 4 + i;
        float4 o;
        o.x = alpha * (acc[i][0] + bias[col + 0]);
        o.y = alpha * (acc[i][1] + bias[col + 1]);
        o.z = alpha * (acc[i][2] + bias[col + 2]);
        o.w = alpha * (acc[i][3] + bias[col + 3]);
        if (resid) {
            const float4 r = *reinterpret_cast<const float4*>(resid + row * ldc + col);
            o.x += r.x; o.y += r.y; o.z += r.z; o.w += r.w;
        }
        *reinterpret_cast<float4*>(C + row * ldc + col) = o;
    }
}

// ---------------------------------------------------------------------------
// denom[i] = max_j | sum_b Nt[b][i] * Q[b][j] |   (Nt,Q: (1024, 4096))
// Fused GEMM + abs-row-max; accumulate into denom via atomicMax on uint bits
// (valid ordering for non-negative floats). denom must be pre-zeroed.
// ---------------------------------------------------------------------------
__global__ __launch_bounds__(256) void ntq_absmax_kernel(
    const float* __restrict__ Nt, const float* __restrict__ Q,
    float* __restrict__ denom)
{
    __shared__ float As[16][64];             // As[k][i]
    __shared__ float Bs[16][64];             // Bs[k][j]
    __shared__ unsigned int lmax[64];

    const int t = threadIdx.x;
    if (t < 64) lmax[t] = 0u;
    const int tx = t & 15, ty = t >> 4;
    const int iBase = blockIdx.y * 64;
    const int jBase = blockIdx.x * 64;
    const int lK  = t >> 4;
    const int lN0 = (t & 15) << 2;

    float acc[4][4] = {};

    for (int kb = 0; kb < B_ROWS; kb += 16) {
        const float4 av = *reinterpret_cast<const float4*>(Nt + (long)(kb + lK) * D_HID + iBase + lN0);
        const float4 bv = *reinterpret_cast<const float4*>(Q  + (long)(kb + lK) * D_HID + jBase + lN0);
        *reinterpret_cast<float4*>(&As[lK][lN0]) = av;
        *reinterpret_cast<float4*>(&Bs[lK][lN0]) = bv;
        __syncthreads();
#pragma unroll
        for (int kk = 0; kk < 16; ++kk) {
            const float a0 = As[kk][ty * 4 + 0];
            const float a1 = As[kk][ty * 4 + 1];
            const float a2 = As[kk][ty * 4 + 2];
            const float a3 = As[kk][ty * 4 + 3];
            const float b0 = Bs[kk][tx * 4 + 0];
            const float b1 = Bs[kk][tx * 4 + 1];
            const float b2 = Bs[kk][tx * 4 + 2];
            const float b3 = Bs[kk][tx * 4 + 3];
            acc[0][0] += a0 * b0; acc[0][1] += a0 * b1; acc[0][2] += a0 * b2; acc[0][3] += a0 * b3;
            acc[1][0] += a1 * b0; acc[1][1] += a1 * b1; acc[1][2] += a1 * b2; acc[1][3] += a1 * b3;
            acc[2][0] += a2 * b0; acc[2][1] += a2 * b1; acc[2][2] += a2 * b2; acc[2][3] += a2 * b3;
            acc[3][0] += a3 * b0; acc[3][1] += a3 * b1; acc[3][2] += a3 * b2; acc[3][3] += a3 * b3;
        }
        __syncthreads();
    }

#pragma unroll
    for (int i = 0; i < 4; ++i) {
        const float m = fmaxf(fmaxf(fabsf(acc[i][0]), fabsf(acc[i][1])),
                              fmaxf(fabsf(acc[i][2]), fabsf(acc[i][3])));
        atomicMax(&lmax[ty * 4 + i], __float_as_uint(m));
    }
    __syncthreads();
    if (t < 64)
        atomicMax(reinterpret_cast<unsigned int*>(&denom[iBase + t]), lmax[t]);
}

// ---------------------------------------------------------------------------
// LayerNorm over D_IN per row
// ---------------------------------------------------------------------------
__global__ __launch_bounds__(256) void layernorm_kernel(
    const float* __restrict__ x, const float* __restrict__ w,
    const float* __restrict__ b, float* __restrict__ out)
{
    __shared__ float sh[8];
    const int row = blockIdx.x, t = threadIdx.x;
    const float* xr = x + (long)row * D_IN;
    float v[8];
    float s = 0.f, ss = 0.f;
#pragma unroll
    for (int i = 0; i < 8; ++i) {
        v[i] = xr[t + 256 * i];
        s += v[i];
        ss += v[i] * v[i];
    }
#pragma unroll
    for (int off = 32; off; off >>= 1) {
        s  += __shfl_down(s, off, 64);
        ss += __shfl_down(ss, off, 64);
    }
    const int lane = t & 63, wid = t >> 6;
    if (lane == 0) { sh[wid * 2] = s; sh[wid * 2 + 1] = ss; }
    __syncthreads();
    s = 0.f; ss = 0.f;
#pragma unroll
    for (int i = 0; i < 4; ++i) { s += sh[i * 2]; ss += sh[i * 2 + 1]; }
    const float mu  = s * (1.0f / D_IN);
    const float var = ss * (1.0f / D_IN) - mu * mu;
    const float rs  = rsqrtf(var + LN_EPS);
    float* orow = out + (long)row * D_IN;
#pragma unroll
    for (int i = 0; i < 8; ++i) {
        const int d = t + 256 * i;
        orow[d] = (v[i] - mu) * rs * w[d] + b[d];
    }
}

// ---------------------------------------------------------------------------
// Causal conv1d (K=4, left pad 3) along feature dim + SiLU
// ---------------------------------------------------------------------------
__global__ void conv_silu_kernel(const float* __restrict__ xl,
                                 const float* __restrict__ cw,
                                 const float* __restrict__ cb,
                                 float* __restrict__ out)
{
    const long idx = (long)blockIdx.x * blockDim.x + threadIdx.x;
    if (idx >= (long)B_ROWS * D_UP) return;
    const int d = (int)(idx & (D_UP - 1));
    const float w0 = cw[0], w1 = cw[1], w2 = cw[2], w3 = cw[3];
    float acc = cb[0] + w3 * xl[idx];
    if (d >= 1) acc += w2 * xl[idx - 1];
    if (d >= 2) acc += w1 * xl[idx - 2];
    if (d >= 3) acc += w0 * xl[idx - 3];
    out[idx] = siluf_(acc);
}

// ---------------------------------------------------------------------------
// Stabilized exponential gating -> writes m_t, c_t, n_t (directly to d_out)
// ---------------------------------------------------------------------------
__global__ void gating_kernel(const float* __restrict__ it, const float* __restrict__ ft,
                              const float* __restrict__ mp, const float* __restrict__ cp,
                              const float* __restrict__ np_, const float* __restrict__ kk,
                              const float* __restrict__ vv,
                              float* __restrict__ mt, float* __restrict__ ct,
                              float* __restrict__ nt)
{
    const long idx = (long)blockIdx.x * blockDim.x + threadIdx.x;
    if (idx >= (long)B_ROWS * D_HID) return;
    const float i_t = it[idx];
    const float f_t = ft[idx] + mp[idx];
    const float m_t = fmaxf(f_t, i_t);
    const float i_g = expf(i_t - m_t);
    const float f_g = expf(f_t - m_t);
    const float kv  = kk[idx];
    ct[idx] = f_g * cp[idx] + i_g * (vv[idx] * kv);
    nt[idx] = f_g * np_[idx] + i_g * kv;
    mt[idx] = m_t;
}

// ---------------------------------------------------------------------------
// h_t = sigmoid(o_pre) * c_t * q / denom[d]
// ---------------------------------------------------------------------------
__global__ void hgate_kernel(const float* __restrict__ op, const float* __restrict__ ct,
                             const float* __restrict__ q, const float* __restrict__ denom,
                             float* __restrict__ ht)
{
    const long idx = (long)blockIdx.x * blockDim.x + threadIdx.x;
    if (idx >= (long)B_ROWS * D_HID) return;
    const int d = (int)(idx & (D_HID - 1));
    ht[idx] = sigmoidf_(op[idx]) * ct[idx] * q[idx] / denom[d];
}

// ---------------------------------------------------------------------------
// GroupNorm(NH groups of HS) + affine + skip + silu-gate -> tmp
// One block (128 thr) per (row, head) group.
// ---------------------------------------------------------------------------
__global__ __launch_bounds__(128) void gnorm_mix_kernel(
    const float* __restrict__ ht, const float* __restrict__ gw,
    const float* __restrict__ gb, const float* __restrict__ xskip,
    const float* __restrict__ xupR, float* __restrict__ out)
{
    __shared__ float sh[4];
    const int b = blockIdx.x >> 3, h = blockIdx.x & 7;
    const int t = threadIdx.x;
    const long base = (long)b * D_HID + h * HS;
    float v[4];
    float s = 0.f, ss = 0.f;
#pragma unroll
    for (int i = 0; i < 4; ++i) {
        v[i] = ht[base + t + 128 * i];
        s += v[i];
        ss += v[i] * v[i];
    }
#pragma unroll
    for (int off = 32; off; off >>= 1) {
        s  += __shfl_down(s, off, 64);
        ss += __shfl_down(ss, off, 64);
    }
    if ((t & 63) == 0) { sh[(t >> 6) * 2] = s; sh[(t >> 6) * 2 + 1] = ss; }
    __syncthreads();
    s = sh[0] + sh[2];
    ss = sh[1] + sh[3];
    const float mu  = s * (1.0f / HS);
    const float var = ss * (1.0f / HS) - mu * mu;
    const float rs  = rsqrtf(var + LN_EPS);
#pragma unroll
    for (int i = 0; i < 4; ++i) {
        const int  dg = h * HS + t + 128 * i;
        const long ix = base + t + 128 * i;
        const float g = (v[i] - mu) * rs * gw[dg] + gb[dg];
        out[ix] = (g + xskip[ix]) * siluf_(xupR[ix]);
    }
}

// ---------------------------------------------------------------------------
extern "C" void kernel_launch(void* const* d_in, const int* in_sizes, int n_in,
                              void* d_out, int out_size, void* d_ws, size_t ws_size,
                              hipStream_t stream)
{
    const float* x      = (const float*)d_in[0];
    // d_in[1] = h_prev (unused by forward)
    const float* c_prev = (const float*)d_in[2];
    const float* n_prev = (const float*)d_in[3];
    const float* m_prev = (const float*)d_in[4];
    const float* ln_w   = (const float*)d_in[5];
    const float* ln_b   = (const float*)d_in[6];
    const float* upL_w  = (const float*)d_in[7];
    const float* upL_b  = (const float*)d_in[8];
    const float* upR_w  = (const float*)d_in[9];
    const float* upR_b  = (const float*)d_in[10];
    const float* conv_w = (const float*)d_in[11];
    const float* conv_b = (const float*)d_in[12];
    const float* skip_w = (const float*)d_in[13];
    const float* skip_b = (const float*)d_in[14];
    const float* wq     = (const float*)d_in[15];
    const float* bq     = (const float*)d_in[16];
    const float* wk     = (const float*)d_in[17];
    const float* bk     = (const float*)d_in[18];
    const float* wv     = (const float*)d_in[19];
    const float* bv     = (const float*)d_in[20];
    const float* wi_w   = (const float*)d_in[21];
    const float* wi_b   = (const float*)d_in[22];
    const float* wf_w   = (const float*)d_in[23];
    const float* wf_b   = (const float*)d_in[24];
    const float* wo_w   = (const float*)d_in[25];
    const float* wo_b   = (const float*)d_in[26];
    const float* gn_w   = (const float*)d_in[27];
    const float* gn_b   = (const float*)d_in[28];
    const float* down_w = (const float*)d_in[29];
    const float* down_b = (const float*)d_in[30];

    float* out     = (float*)d_out;
    float* final_o = out;                       // (1024, 2048)
    float* ht      = final_o + 2097152;         // (1024, 4096)
    float* ct      = ht + 4194304;
    float* nt      = ct + 4194304;
    float* mt      = nt + 4194304;

    float* ws    = (float*)d_ws;
    float* xnorm = ws;                  // 2,097,152
    float* xupL  = xnorm + 2097152;     // 4,194,304 each below
    float* xupR  = xupL + 4194304;
    float* xconv = xupR + 4194304;
    float* xskip = xconv + 4194304;
    float* qb    = xskip + 4194304;
    float* kb    = qb + 4194304;
    float* vb    = kb + 4194304;
    float* itb   = vb + 4194304;
    float* ftb   = itb + 4194304;
    float* opb   = ftb + 4194304;
    float* denom = opb + 4194304;       // 4096
    float* tmp   = kb;                  // reuse k buffer after gating

    const float kscale = 1.0f / sqrtf((float)HS);

    // 1. LayerNorm
    layernorm_kernel<<<B_ROWS, 256, 0, stream>>>(x, ln_w, ln_b, xnorm);

    // 2. up-projections
    sgemm_kernel<<<dim3(D_UP / 64, B_ROWS / 64, 1), 256, 0, stream>>>(
        xnorm, upL_w, upL_b, nullptr, xupL, D_IN, D_IN, D_UP, D_UP, 0, 0, 0, 0, 1.0f);
    sgemm_kernel<<<dim3(D_HID / 64, B_ROWS / 64, 1), 256, 0, stream>>>(
        xnorm, upR_w, upR_b, nullptr, xupR, D_IN, D_IN, D_HID, D_HID, 0, 0, 0, 0, 1.0f);

    // 3. causal conv + silu
    conv_silu_kernel<<<(B_ROWS * D_UP) / 256, 256, 0, stream>>>(xupL, conv_w, conv_b, xconv);

    // 4. skip projection
    sgemm_kernel<<<dim3(D_HID / 64, B_ROWS / 64, 1), 256, 0, stream>>>(
        xconv, skip_w, skip_b, nullptr, xskip, D_UP, D_UP, D_HID, D_HID, 0, 0, 0, 0, 1.0f);

    // 5. block-diagonal q, k, v (batched over heads via blockIdx.z)
    sgemm_kernel<<<dim3(HS / 64, B_ROWS / 64, NH), 256, 0, stream>>>(
        xconv, wq, bq, nullptr, qb, HS, D_UP, HS, D_HID, HS, (long)HS * HS, HS, HS, 1.0f);
    sgemm_kernel<<<dim3(HS / 64, B_ROWS / 64, NH), 256, 0, stream>>>(
        xconv, wk, bk, nullptr, kb, HS, D_UP, HS, D_HID, HS, (long)HS * HS, HS, HS, kscale);
    sgemm_kernel<<<dim3(HS / 64, B_ROWS / 64, NH), 256, 0, stream>>>(
        xupL, wv, bv, nullptr, vb, HS, D_UP, HS, D_HID, HS, (long)HS * HS, HS, HS, 1.0f);

    // 6. gate projections
    sgemm_kernel<<<dim3(D_HID / 64, B_ROWS / 64, 1), 256, 0, stream>>>(
        xconv, wi_w, wi_b, nullptr, itb, D_UP, D_UP, D_HID, D_HID, 0, 0, 0, 0, 1.0f);
    sgemm_kernel<<<dim3(D_HID / 64, B_ROWS / 64, 1), 256, 0, stream>>>(
        xconv, wf_w, wf_b, nullptr, ftb, D_UP, D_UP, D_HID, D_HID, 0, 0, 0, 0, 1.0f);
    sgemm_kernel<<<dim3(D_HID / 64, B_ROWS / 64, 1), 256, 0, stream>>>(
        xupL, wo_w, wo_b, nullptr, opb, D_UP, D_UP, D_HID, D_HID, 0, 0, 0, 0, 1.0f);

    // 7. exponential gating -> m_t, c_t, n_t (direct to d_out)
    gating_kernel<<<(B_ROWS * D_HID) / 256, 256, 0, stream>>>(
        itb, ftb, m_prev, c_prev, n_prev, kb, vb, mt, ct, nt);

    // 8. denom = rowwise max |n_t^T q|
    hipMemsetAsync(denom, 0, D_HID * sizeof(float), stream);
    ntq_absmax_kernel<<<dim3(D_HID / 64, D_HID / 64, 1), 256, 0, stream>>>(nt, qb, denom);

    // 9. h_t
    hgate_kernel<<<(B_ROWS * D_HID) / 256, 256, 0, stream>>>(opb, ct, qb, denom, ht);

    // 10. GroupNorm + skip + silu gate
    gnorm_mix_kernel<<<B_ROWS * NH, 128, 0, stream>>>(ht, gn_w, gn_b, xskip, xupR, tmp);

    // 11. down-projection + residual -> final
    sgemm_kernel<<<dim3(D_IN / 64, B_ROWS / 64, 1), 256, 0, stream>>>(
        tmp, down_w, down_b, x, final_o, D_HID, D_HID, D_IN, D_IN, 0, 0, 0, 0, 1.0f);
}

// Round 3
// 716.052 us; speedup vs baseline: 5.3841x; 5.3841x over previous
//
#include <hip/hip_runtime.h>
#include <math.h>

#define B_ROWS 1024
#define D_IN   2048
#define D_HID  4096
#define D_UP   4096
#define NH     8
#define HS     512
#define LN_EPS 1e-5f

typedef __attribute__((ext_vector_type(8))) short bf16x8_t;
typedef __attribute__((ext_vector_type(4))) float f32x4_t;
typedef __attribute__((ext_vector_type(4))) unsigned short us4_t;

__device__ __forceinline__ unsigned short f2bf(float f) {
    unsigned int u = __float_as_uint(f);
    u += 0x7fffu + ((u >> 16) & 1u);
    return (unsigned short)(u >> 16);
}
__device__ __forceinline__ float bf2f(unsigned short u) {
    return __uint_as_float(((unsigned int)u) << 16);
}
__device__ __forceinline__ float sigmoidf_(float x) { return 1.0f / (1.0f + expf(-x)); }
__device__ __forceinline__ float siluf_(float x)    { return x / (1.0f + expf(-x)); }

// ---------------------------------------------------------------------------
// bf16 MFMA GEMM: C = epi(A @ B + bias)
// A: (M,K) bf16 row-major (lda). Bt: (N,K) bf16 row-major (ldbt) — i.e. B^T.
// Tile BMx128, BK=32, 256 thr = 4 waves in 2x2; wave tile (BM/2)x64.
// EPI: 0=bias->f32  2=(bias)*alpha->f32  3=abs-row-max->denom  4=bias+resid->f32
//      5=bias->bf16
// ---------------------------------------------------------------------------
template<int BM, int EPI>
__global__ __launch_bounds__(256) void mgemm(
    const unsigned short* __restrict__ A, const unsigned short* __restrict__ Bt,
    const float* __restrict__ bias, const float* __restrict__ resid,
    float* __restrict__ C, unsigned short* __restrict__ C2,
    float* __restrict__ denom,
    int K, int lda, int ldbt, int ldc,
    long aB, long wB, long bB, long cB, float alpha)
{
    constexpr int MR = BM / 32;   // 16x16 m-frags per wave
    constexpr int AP = BM / 64;   // staging passes for A
    const int bz = blockIdx.z;
    A  += (long)bz * aB;
    Bt += (long)bz * wB;
    if (EPI != 3) bias += (long)bz * bB;
    if (EPI == 5) { C2 += (long)bz * cB; } else if (EPI != 3) { C += (long)bz * cB; }

    __shared__ __align__(16) unsigned short As[2][BM][40];
    __shared__ __align__(16) unsigned short Bs[2][128][40];

    const int t = threadIdx.x;
    const int w = t >> 6, l = t & 63;
    const int wr = w >> 1, wc = w & 1;
    const long rowA = (long)blockIdx.y * BM;
    const long rowB = (long)blockIdx.x * 128;

    const int lr = t >> 2;            // staging row 0..63
    const int lc = (t & 3) << 3;      // staging col (elements)
    const unsigned short* Ag = A  + (rowA + lr) * (long)lda  + lc;
    const unsigned short* Bg = Bt + (rowB + lr) * (long)ldbt + lc;

    const int lm = l & 15;            // frag row-in-tile
    const int lk = (l >> 4) * 8;      // frag k-offset

    f32x4_t acc[MR][4];
#pragma unroll
    for (int mi = 0; mi < MR; ++mi)
#pragma unroll
        for (int ni = 0; ni < 4; ++ni) acc[mi][ni] = (f32x4_t)0.0f;

    bf16x8_t ra[AP], rb[2];

    // prologue: load + store tile 0
#pragma unroll
    for (int p = 0; p < AP; ++p) ra[p] = *(const bf16x8_t*)(Ag + (long)p * 64 * lda);
#pragma unroll
    for (int p = 0; p < 2;  ++p) rb[p] = *(const bf16x8_t*)(Bg + (long)p * 64 * ldbt);
#pragma unroll
    for (int p = 0; p < AP; ++p) *(bf16x8_t*)&As[0][lr + p * 64][lc] = ra[p];
#pragma unroll
    for (int p = 0; p < 2;  ++p) *(bf16x8_t*)&Bs[0][lr + p * 64][lc] = rb[p];
    __syncthreads();

    const int nsteps = K >> 5;
    for (int ti = 0; ti < nsteps; ++ti) {
        const int cur = ti & 1;
        if (ti + 1 < nsteps) {
            const int kb = (ti + 1) << 5;
#pragma unroll
            for (int p = 0; p < AP; ++p) ra[p] = *(const bf16x8_t*)(Ag + (long)p * 64 * lda  + kb);
#pragma unroll
            for (int p = 0; p < 2;  ++p) rb[p] = *(const bf16x8_t*)(Bg + (long)p * 64 * ldbt + kb);
        }
        bf16x8_t af[MR], bfr[4];
#pragma unroll
        for (int mi = 0; mi < MR; ++mi)
            af[mi] = *(const bf16x8_t*)&As[cur][wr * (BM / 2) + mi * 16 + lm][lk];
#pragma unroll
        for (int ni = 0; ni < 4; ++ni)
            bfr[ni] = *(const bf16x8_t*)&Bs[cur][wc * 64 + ni * 16 + lm][lk];
#pragma unroll
        for (int mi = 0; mi < MR; ++mi)
#pragma unroll
            for (int ni = 0; ni < 4; ++ni)
                acc[mi][ni] = __builtin_amdgcn_mfma_f32_16x16x32_bf16(
                    af[mi], bfr[ni], acc[mi][ni], 0, 0, 0);
        if (ti + 1 < nsteps) {
            const int nxt = cur ^ 1;
#pragma unroll
            for (int p = 0; p < AP; ++p) *(bf16x8_t*)&As[nxt][lr + p * 64][lc] = ra[p];
#pragma unroll
            for (int p = 0; p < 2;  ++p) *(bf16x8_t*)&Bs[nxt][lr + p * 64][lc] = rb[p];
        }
        __syncthreads();
    }

    // epilogue. C/D layout: col = lane&15, row = (lane>>4)*4 + reg  [m89-verified]
    const int lr4 = (l >> 4) * 4;
    if (EPI == 3) {
        float rmax[MR][4];
#pragma unroll
        for (int mi = 0; mi < MR; ++mi)
#pragma unroll
            for (int r = 0; r < 4; ++r) {
                float m = 0.0f;
#pragma unroll
                for (int ni = 0; ni < 4; ++ni) m = fmaxf(m, fabsf(acc[mi][ni][r]));
                rmax[mi][r] = m;
            }
#pragma unroll
        for (int off = 1; off < 16; off <<= 1)
#pragma unroll
            for (int mi = 0; mi < MR; ++mi)
#pragma unroll
                for (int r = 0; r < 4; ++r)
                    rmax[mi][r] = fmaxf(rmax[mi][r], __shfl_xor(rmax[mi][r], off, 64));
        if (lm == 0) {
#pragma unroll
            for (int mi = 0; mi < MR; ++mi)
#pragma unroll
                for (int r = 0; r < 4; ++r) {
                    const long m = rowA + wr * (BM / 2) + mi * 16 + lr4 + r;
                    atomicMax((unsigned int*)&denom[m], __float_as_uint(rmax[mi][r]));
                }
        }
        return;
    }
#pragma unroll
    for (int mi = 0; mi < MR; ++mi) {
        const long m0 = rowA + wr * (BM / 2) + mi * 16 + lr4;
#pragma unroll
        for (int ni = 0; ni < 4; ++ni) {
            const long n = rowB + wc * 64 + ni * 16 + lm;
            const float bv = bias[n];
#pragma unroll
            for (int r = 0; r < 4; ++r) {
                float v = acc[mi][ni][r] + bv;
                if (EPI == 2) v *= alpha;
                const long m = m0 + r;
                if (EPI == 4) v += resid[m * ldc + n];
                if (EPI == 5) C2[m * ldc + n] = f2bf(v);
                else          C [m * ldc + n] = v;
            }
        }
    }
}

// ---------------------------------------------------------------------------
// Transpose + f32->bf16: X (R,C) f32 -> XT (C,R) bf16. Batched via blockIdx.z.
// ---------------------------------------------------------------------------
__global__ __launch_bounds__(256) void transpose_bf(
    const float* __restrict__ X, unsigned short* __restrict__ XT, int R, int C)
{
    __shared__ float tile[64][65];
    X  += (long)blockIdx.z * R * C;
    XT += (long)blockIdx.z * R * C;
    const int t = threadIdx.x;
    const long r0 = (long)blockIdx.y * 64;
    const long c0 = (long)blockIdx.x * 64;
    const int tr = t >> 4;            // 0..15
    const int tc = (t & 15) << 2;     // 0..60
#pragma unroll
    for (int p = 0; p < 4; ++p) {
        const float4 v = *(const float4*)(X + (r0 + tr + p * 16) * C + c0 + tc);
        tile[tr + p * 16][tc + 0] = v.x;
        tile[tr + p * 16][tc + 1] = v.y;
        tile[tr + p * 16][tc + 2] = v.z;
        tile[tr + p * 16][tc + 3] = v.w;
    }
    __syncthreads();
#pragma unroll
    for (int p = 0; p < 4; ++p) {
        const int cc = tr + p * 16;
        us4_t o;
        o.x = f2bf(tile[tc + 0][cc]);
        o.y = f2bf(tile[tc + 1][cc]);
        o.z = f2bf(tile[tc + 2][cc]);
        o.w = f2bf(tile[tc + 3][cc]);
        *(us4_t*)(XT + (c0 + cc) * (long)R + r0 + tc) = o;
    }
}

// ---------------------------------------------------------------------------
// LayerNorm over D_IN per row -> bf16
// ---------------------------------------------------------------------------
__global__ __launch_bounds__(256) void layernorm_kernel(
    const float* __restrict__ x, const float* __restrict__ w,
    const float* __restrict__ b, unsigned short* __restrict__ out)
{
    __shared__ float sh[8];
    const int row = blockIdx.x, t = threadIdx.x;
    const float* xr = x + (long)row * D_IN;
    float v[8];
    float s = 0.f, ss = 0.f;
#pragma unroll
    for (int i = 0; i < 8; ++i) {
        v[i] = xr[t + 256 * i];
        s += v[i];
        ss += v[i] * v[i];
    }
#pragma unroll
    for (int off = 32; off; off >>= 1) {
        s  += __shfl_down(s, off, 64);
        ss += __shfl_down(ss, off, 64);
    }
    const int lane = t & 63, wid = t >> 6;
    if (lane == 0) { sh[wid * 2] = s; sh[wid * 2 + 1] = ss; }
    __syncthreads();
    s = 0.f; ss = 0.f;
#pragma unroll
    for (int i = 0; i < 4; ++i) { s += sh[i * 2]; ss += sh[i * 2 + 1]; }
    const float mu  = s * (1.0f / D_IN);
    const float var = ss * (1.0f / D_IN) - mu * mu;
    const float rs  = rsqrtf(var + LN_EPS);
    unsigned short* orow = out + (long)row * D_IN;
#pragma unroll
    for (int i = 0; i < 8; ++i) {
        const int d = t + 256 * i;
        orow[d] = f2bf((v[i] - mu) * rs * w[d] + b[d]);
    }
}

// ---------------------------------------------------------------------------
// Causal conv1d (K=4, left pad 3) along feature dim + SiLU.  bf16 -> bf16
// ---------------------------------------------------------------------------
__global__ void conv_silu_kernel(const unsigned short* __restrict__ xl,
                                 const float* __restrict__ cw,
                                 const float* __restrict__ cb,
                                 unsigned short* __restrict__ out)
{
    const long idx = (long)blockIdx.x * blockDim.x + threadIdx.x;
    if (idx >= (long)B_ROWS * D_UP) return;
    const int d = (int)(idx & (D_UP - 1));
    const float w0 = cw[0], w1 = cw[1], w2 = cw[2], w3 = cw[3];
    float acc = cb[0] + w3 * bf2f(xl[idx]);
    if (d >= 1) acc += w2 * bf2f(xl[idx - 1]);
    if (d >= 2) acc += w1 * bf2f(xl[idx - 2]);
    if (d >= 3) acc += w0 * bf2f(xl[idx - 3]);
    out[idx] = f2bf(siluf_(acc));
}

// ---------------------------------------------------------------------------
// Stabilized exponential gating -> m_t, c_t, n_t (direct to d_out)
// ---------------------------------------------------------------------------
__global__ void gating_kernel(const float* __restrict__ it, const float* __restrict__ ft,
                              const float* __restrict__ mp, const float* __restrict__ cp,
                              const float* __restrict__ np_, const float* __restrict__ kk,
                              const float* __restrict__ vv,
                              float* __restrict__ mt, float* __restrict__ ct,
                              float* __restrict__ nt)
{
    const long idx = (long)blockIdx.x * blockDim.x + threadIdx.x;
    if (idx >= (long)B_ROWS * D_HID) return;
    const float i_t = it[idx];
    const float f_t = ft[idx] + mp[idx];
    const float m_t = fmaxf(f_t, i_t);
    const float i_g = expf(i_t - m_t);
    const float f_g = expf(f_t - m_t);
    const float kv  = kk[idx];
    ct[idx] = f_g * cp[idx] + i_g * (vv[idx] * kv);
    nt[idx] = f_g * np_[idx] + i_g * kv;
    mt[idx] = m_t;
}

// ---------------------------------------------------------------------------
// h_t = sigmoid(o_pre) * c_t * q / denom[d]
// ---------------------------------------------------------------------------
__global__ void hgate_kernel(const float* __restrict__ op, const float* __restrict__ ct,
                             const float* __restrict__ q, const float* __restrict__ denom,
                             float* __restrict__ ht)
{
    const long idx = (long)blockIdx.x * blockDim.x + threadIdx.x;
    if (idx >= (long)B_ROWS * D_HID) return;
    const int d = (int)(idx & (D_HID - 1));
    ht[idx] = sigmoidf_(op[idx]) * ct[idx] * q[idx] / denom[d];
}

// ---------------------------------------------------------------------------
// GroupNorm(NH,HS) + affine + skip + silu-gate -> bf16
// ---------------------------------------------------------------------------
__global__ __launch_bounds__(128) void gnorm_mix_kernel(
    const float* __restrict__ ht, const float* __restrict__ gw,
    const float* __restrict__ gb, const float* __restrict__ xskip,
    const float* __restrict__ xupR, unsigned short* __restrict__ out)
{
    __shared__ float sh[4];
    const int b = blockIdx.x >> 3, h = blockIdx.x & 7;
    const int t = threadIdx.x;
    const long base = (long)b * D_HID + h * HS;
    float v[4];
    float s = 0.f, ss = 0.f;
#pragma unroll
    for (int i = 0; i < 4; ++i) {
        v[i] = ht[base + t + 128 * i];
        s += v[i];
        ss += v[i] * v[i];
    }
#pragma unroll
    for (int off = 32; off; off >>= 1) {
        s  += __shfl_down(s, off, 64);
        ss += __shfl_down(ss, off, 64);
    }
    if ((t & 63) == 0) { sh[(t >> 6) * 2] = s; sh[(t >> 6) * 2 + 1] = ss; }
    __syncthreads();
    s = sh[0] + sh[2];
    ss = sh[1] + sh[3];
    const float mu  = s * (1.0f / HS);
    const float var = ss * (1.0f / HS) - mu * mu;
    const float rs  = rsqrtf(var + LN_EPS);
#pragma unroll
    for (int i = 0; i < 4; ++i) {
        const int  dg = h * HS + t + 128 * i;
        const long ix = base + t + 128 * i;
        const float g = (v[i] - mu) * rs * gw[dg] + gb[dg];
        out[ix] = f2bf((g + xskip[ix]) * siluf_(xupR[ix]));
    }
}

// ---------------------------------------------------------------------------
extern "C" void kernel_launch(void* const* d_in, const int* in_sizes, int n_in,
                              void* d_out, int out_size, void* d_ws, size_t ws_size,
                              hipStream_t stream)
{
    const float* x      = (const float*)d_in[0];
    const float* c_prev = (const float*)d_in[2];
    const float* n_prev = (const float*)d_in[3];
    const float* m_prev = (const float*)d_in[4];
    const float* ln_w   = (const float*)d_in[5];
    const float* ln_b   = (const float*)d_in[6];
    const float* upL_w  = (const float*)d_in[7];
    const float* upL_b  = (const float*)d_in[8];
    const float* upR_w  = (const float*)d_in[9];
    const float* upR_b  = (const float*)d_in[10];
    const float* conv_w = (const float*)d_in[11];
    const float* conv_b = (const float*)d_in[12];
    const float* skip_w = (const float*)d_in[13];
    const float* skip_b = (const float*)d_in[14];
    const float* wq     = (const float*)d_in[15];
    const float* bq     = (const float*)d_in[16];
    const float* wk     = (const float*)d_in[17];
    const float* bk     = (const float*)d_in[18];
    const float* wv     = (const float*)d_in[19];
    const float* bv     = (const float*)d_in[20];
    const float* wi_w   = (const float*)d_in[21];
    const float* wi_b   = (const float*)d_in[22];
    const float* wf_w   = (const float*)d_in[23];
    const float* wf_b   = (const float*)d_in[24];
    const float* wo_w   = (const float*)d_in[25];
    const float* wo_b   = (const float*)d_in[26];
    const float* gn_w   = (const float*)d_in[27];
    const float* gn_b   = (const float*)d_in[28];
    const float* down_w = (const float*)d_in[29];
    const float* down_b = (const float*)d_in[30];

    float* out     = (float*)d_out;
    float* final_o = out;                       // (1024, 2048)
    float* ht      = final_o + 2097152;         // (1024, 4096)
    float* ct      = ht + 4194304;
    float* nt      = ct + 4194304;
    float* mt      = nt + 4194304;

    // workspace layout (float units). Total ≈ 47.2M floats (< proven 48.2M).
    float* ws    = (float*)d_ws;
    float* xupR  = ws;                     // 4M f32
    float* xskip = ws + 1 * 4194304;
    float* qb    = ws + 2 * 4194304;
    float* kb    = ws + 3 * 4194304;       // tmp_bf aliases after gating
    float* vb    = ws + 4 * 4194304;
    float* itb   = ws + 5 * 4194304;       // ntT aliases after gating
    float* ftb   = ws + 6 * 4194304;       // qT aliases after gating
    float* opb   = ws + 7 * 4194304;
    unsigned short* xnorm_bf = (unsigned short*)(ws + 8 * 4194304);               // 2M el
    unsigned short* xupL_bf  = (unsigned short*)(ws + 8 * 4194304 + 1048576);     // 4M el
    unsigned short* xconv_bf = (unsigned short*)(ws + 8 * 4194304 + 3 * 1048576); // 4M el
    float* denom = ws + 8 * 4194304 + 5 * 1048576;                                // 4096
    unsigned short* WT = (unsigned short*)(ws + 8 * 4194304 + 5 * 1048576 + 8192); // 16.8M el
    unsigned short* tmp_bf = (unsigned short*)kb;
    unsigned short* ntT    = (unsigned short*)itb;
    unsigned short* qT     = (unsigned short*)ftb;

    const float kscale = 1.0f / sqrtf((float)HS);
    const long HS2 = (long)HS * HS;

    // 1. LayerNorm -> bf16
    layernorm_kernel<<<B_ROWS, 256, 0, stream>>>(x, ln_w, ln_b, xnorm_bf);

    // 2. upL: (1024,2048)@(2048,4096) -> bf16
    transpose_bf<<<dim3(D_UP / 64, D_IN / 64, 1), 256, 0, stream>>>(upL_w, WT, D_IN, D_UP);
    mgemm<128, 5><<<dim3(D_UP / 128, B_ROWS / 128, 1), 256, 0, stream>>>(
        xnorm_bf, WT, upL_b, nullptr, nullptr, xupL_bf, nullptr,
        D_IN, D_IN, D_IN, D_UP, 0, 0, 0, 0, 1.0f);

    // 3. causal conv + silu -> bf16
    conv_silu_kernel<<<(B_ROWS * D_UP) / 256, 256, 0, stream>>>(xupL_bf, conv_w, conv_b, xconv_bf);

    // 4. upR -> f32
    transpose_bf<<<dim3(D_HID / 64, D_IN / 64, 1), 256, 0, stream>>>(upR_w, WT, D_IN, D_HID);
    mgemm<128, 0><<<dim3(D_HID / 128, B_ROWS / 128, 1), 256, 0, stream>>>(
        xnorm_bf, WT, upR_b, nullptr, xupR, nullptr, nullptr,
        D_IN, D_IN, D_IN, D_HID, 0, 0, 0, 0, 1.0f);

    // 5. skip -> f32
    transpose_bf<<<dim3(D_HID / 64, D_UP / 64, 1), 256, 0, stream>>>(skip_w, WT, D_UP, D_HID);
    mgemm<128, 0><<<dim3(D_HID / 128, B_ROWS / 128, 1), 256, 0, stream>>>(
        xconv_bf, WT, skip_b, nullptr, xskip, nullptr, nullptr,
        D_UP, D_UP, D_UP, D_HID, 0, 0, 0, 0, 1.0f);

    // 6. block-diagonal q, k, v (head-batched via blockIdx.z)
    transpose_bf<<<dim3(8, 8, NH), 256, 0, stream>>>(wq, WT, HS, HS);
    mgemm<128, 0><<<dim3(HS / 128, B_ROWS / 128, NH), 256, 0, stream>>>(
        xconv_bf, WT, bq, nullptr, qb, nullptr, nullptr,
        HS, D_UP, HS, D_HID, HS, HS2, HS, HS, 1.0f);
    transpose_bf<<<dim3(8, 8, NH), 256, 0, stream>>>(wk, WT, HS, HS);
    mgemm<128, 2><<<dim3(HS / 128, B_ROWS / 128, NH), 256, 0, stream>>>(
        xconv_bf, WT, bk, nullptr, kb, nullptr, nullptr,
        HS, D_UP, HS, D_HID, HS, HS2, HS, HS, kscale);
    transpose_bf<<<dim3(8, 8, NH), 256, 0, stream>>>(wv, WT, HS, HS);
    mgemm<128, 0><<<dim3(HS / 128, B_ROWS / 128, NH), 256, 0, stream>>>(
        xupL_bf, WT, bv, nullptr, vb, nullptr, nullptr,
        HS, D_UP, HS, D_HID, HS, HS2, HS, HS, 1.0f);

    // 7. gate projections -> f32
    transpose_bf<<<dim3(D_HID / 64, D_UP / 64, 1), 256, 0, stream>>>(wi_w, WT, D_UP, D_HID);
    mgemm<128, 0><<<dim3(D_HID / 128, B_ROWS / 128, 1), 256, 0, stream>>>(
        xconv_bf, WT, wi_b, nullptr, itb, nullptr, nullptr,
        D_UP, D_UP, D_UP, D_HID, 0, 0, 0, 0, 1.0f);
    transpose_bf<<<dim3(D_HID / 64, D_UP / 64, 1), 256, 0, stream>>>(wf_w, WT, D_UP, D_HID);
    mgemm<128, 0><<<dim3(D_HID / 128, B_ROWS / 128, 1), 256, 0, stream>>>(
        xconv_bf, WT, wf_b, nullptr, ftb, nullptr, nullptr,
        D_UP, D_UP, D_UP, D_HID, 0, 0, 0, 0, 1.0f);
    transpose_bf<<<dim3(D_HID / 64, D_UP / 64, 1), 256, 0, stream>>>(wo_w, WT, D_UP, D_HID);
    mgemm<128, 0><<<dim3(D_HID / 128, B_ROWS / 128, 1), 256, 0, stream>>>(
        xupL_bf, WT, wo_b, nullptr, opb, nullptr, nullptr,
        D_UP, D_UP, D_UP, D_HID, 0, 0, 0, 0, 1.0f);

    // 8. gating -> m_t, c_t, n_t
    gating_kernel<<<(B_ROWS * D_HID) / 256, 256, 0, stream>>>(
        itb, ftb, m_prev, c_prev, n_prev, kb, vb, mt, ct, nt);

    // 9. denom = rowwise max |n_t^T q| via bf16 MFMA + fused absmax epilogue
    transpose_bf<<<dim3(D_HID / 64, B_ROWS / 64, 1), 256, 0, stream>>>(nt, ntT, B_ROWS, D_HID);
    transpose_bf<<<dim3(D_HID / 64, B_ROWS / 64, 1), 256, 0, stream>>>(qb, qT, B_ROWS, D_HID);
    hipMemsetAsync(denom, 0, D_HID * sizeof(float), stream);
    mgemm<128, 3><<<dim3(D_HID / 128, D_HID / 128, 1), 256, 0, stream>>>(
        ntT, qT, nullptr, nullptr, nullptr, nullptr, denom,
        B_ROWS, B_ROWS, B_ROWS, 0, 0, 0, 0, 0, 1.0f);

    // 10. h_t
    hgate_kernel<<<(B_ROWS * D_HID) / 256, 256, 0, stream>>>(opb, ct, qb, denom, ht);

    // 11. GroupNorm + skip + silu gate -> bf16
    gnorm_mix_kernel<<<B_ROWS * NH, 128, 0, stream>>>(ht, gn_w, gn_b, xskip, xupR, tmp_bf);

    // 12. down-projection + residual -> final
    transpose_bf<<<dim3(D_IN / 64, D_HID / 64, 1), 256, 0, stream>>>(down_w, WT, D_HID, D_IN);
    mgemm<64, 4><<<dim3(D_IN / 128, B_ROWS / 64, 1), 256, 0, stream>>>(
        tmp_bf, WT, down_b, x, final_o, nullptr, nullptr,
        D_HID, D_HID, D_HID, D_IN, 0, 0, 0, 0, 1.0f);
}

// Round 4
// 600.739 us; speedup vs baseline: 6.4176x; 1.1920x over previous
//
#include <hip/hip_runtime.h>
#include <math.h>

#define B_ROWS 1024
#define D_IN   2048
#define D_HID  4096
#define D_UP   4096
#define NH     8
#define HS     512
#define LN_EPS 1e-5f

typedef __attribute__((ext_vector_type(8))) short bf16x8_t;
typedef __attribute__((ext_vector_type(4))) float f32x4_t;
typedef __attribute__((ext_vector_type(4))) unsigned short us4_t;

__device__ __forceinline__ unsigned short f2bf(float f) {
    unsigned int u = __float_as_uint(f);
    u += 0x7fffu + ((u >> 16) & 1u);
    return (unsigned short)(u >> 16);
}
__device__ __forceinline__ float bf2f(unsigned short u) {
    return __uint_as_float(((unsigned int)u) << 16);
}
__device__ __forceinline__ float sigmoidf_(float x) { return 1.0f / (1.0f + expf(-x)); }
__device__ __forceinline__ float siluf_(float x)    { return x / (1.0f + expf(-x)); }

// XCD-aware bijective swizzle of (bx,by); requires gx*gy % 8 == 0 (guarded).
#define XCD_SWZ()                                                        \
    int bx = blockIdx.x, by = blockIdx.y;                                \
    {                                                                    \
        const int gx_ = gridDim.x;                                       \
        const int n_  = gx_ * gridDim.y;                                 \
        if ((n_ & 7) == 0) {                                             \
            int lin = by * gx_ + bx;                                     \
            const int q8 = n_ >> 3;                                      \
            lin = (lin & 7) * q8 + (lin >> 3);                           \
            bx = lin % gx_; by = lin / gx_;                              \
        }                                                                \
    }

// ---------------------------------------------------------------------------
// Multi-chunk bf16 MFMA GEMM. N-dim is split into NCH chunks of (bpc*128)
// columns; each chunk has its own A, Bt, bias, output, epi, alpha.
// A: (M,K) bf16 row-major (lda, shared). Bt: (N,K) bf16 row-major (ldbt).
// Tile 128x128, BK=32, 4 waves 2x2, double-buffered LDS.
// epi: 0 = f32 out (alpha*(acc+bias));  5 = bf16 out.
// Batched over blockIdx.z with strides aB (A column offset), wB, bB, cB.
// ---------------------------------------------------------------------------
struct MGChunk {
    const unsigned short* A;
    const unsigned short* Bt;
    const float* bias;
    float* C;
    unsigned short* C2;
    float alpha;
    int epi;
};

template<int NCH>
__global__ __launch_bounds__(256) void mgemm_mc(
    MGChunk c0, MGChunk c1, MGChunk c2,
    int K, int lda, int ldbt, int ldc, int bpc,
    long aB, long wB, long bB, long cB)
{
    XCD_SWZ();
    const int chid = bx / bpc;
    const int cbx  = bx - chid * bpc;
    const MGChunk ch = (chid == 0) ? c0 : ((NCH > 1 && chid == 1) ? c1 : c2);
    const int bz = blockIdx.z;

    const unsigned short* A  = ch.A  + bz * aB;
    const unsigned short* Bt = ch.Bt + bz * wB;
    const float* bias = ch.bias + bz * bB;

    __shared__ __align__(16) unsigned short As[2][128][40];
    __shared__ __align__(16) unsigned short Bs[2][128][40];

    const int t = threadIdx.x;
    const int w = t >> 6, l = t & 63;
    const int wr = w >> 1, wc = w & 1;
    const long rowA = (long)by * 128;
    const long rowB = (long)cbx * 128;

    const int lr = t >> 2;
    const int lc = (t & 3) << 3;
    const unsigned short* Ag = A  + (rowA + lr) * (long)lda  + lc;
    const unsigned short* Bg = Bt + (rowB + lr) * (long)ldbt + lc;

    const int lm = l & 15;
    const int lk = (l >> 4) * 8;

    f32x4_t acc[4][4];
#pragma unroll
    for (int mi = 0; mi < 4; ++mi)
#pragma unroll
        for (int ni = 0; ni < 4; ++ni) acc[mi][ni] = (f32x4_t)0.0f;

    bf16x8_t ra[2], rb[2];
#pragma unroll
    for (int p = 0; p < 2; ++p) {
        ra[p] = *(const bf16x8_t*)(Ag + (long)p * 64 * lda);
        rb[p] = *(const bf16x8_t*)(Bg + (long)p * 64 * ldbt);
    }
#pragma unroll
    for (int p = 0; p < 2; ++p) {
        *(bf16x8_t*)&As[0][lr + p * 64][lc] = ra[p];
        *(bf16x8_t*)&Bs[0][lr + p * 64][lc] = rb[p];
    }
    __syncthreads();

    const int nsteps = K >> 5;
    for (int ti = 0; ti < nsteps; ++ti) {
        const int cur = ti & 1;
        if (ti + 1 < nsteps) {
            const int kb = (ti + 1) << 5;
#pragma unroll
            for (int p = 0; p < 2; ++p) {
                ra[p] = *(const bf16x8_t*)(Ag + (long)p * 64 * lda  + kb);
                rb[p] = *(const bf16x8_t*)(Bg + (long)p * 64 * ldbt + kb);
            }
        }
        bf16x8_t af[4], bfr[4];
#pragma unroll
        for (int mi = 0; mi < 4; ++mi)
            af[mi] = *(const bf16x8_t*)&As[cur][wr * 64 + mi * 16 + lm][lk];
#pragma unroll
        for (int ni = 0; ni < 4; ++ni)
            bfr[ni] = *(const bf16x8_t*)&Bs[cur][wc * 64 + ni * 16 + lm][lk];
#pragma unroll
        for (int mi = 0; mi < 4; ++mi)
#pragma unroll
            for (int ni = 0; ni < 4; ++ni)
                acc[mi][ni] = __builtin_amdgcn_mfma_f32_16x16x32_bf16(
                    af[mi], bfr[ni], acc[mi][ni], 0, 0, 0);
        if (ti + 1 < nsteps) {
            const int nxt = cur ^ 1;
#pragma unroll
            for (int p = 0; p < 2; ++p) {
                *(bf16x8_t*)&As[nxt][lr + p * 64][lc] = ra[p];
                *(bf16x8_t*)&Bs[nxt][lr + p * 64][lc] = rb[p];
            }
        }
        __syncthreads();
    }

    // C/D layout: col = lane&15, row = (lane>>4)*4 + reg
    const int lr4 = (l >> 4) * 4;
    const float alpha = ch.alpha;
#pragma unroll
    for (int mi = 0; mi < 4; ++mi) {
        const long m0 = rowA + wr * 64 + mi * 16 + lr4;
#pragma unroll
        for (int ni = 0; ni < 4; ++ni) {
            const long n = rowB + wc * 64 + ni * 16 + lm;
            const float bv = bias[n];
#pragma unroll
            for (int r = 0; r < 4; ++r) {
                const float v = (acc[mi][ni][r] + bv) * alpha;
                const long m = m0 + r;
                if (ch.epi == 5) (ch.C2 + bz * cB)[m * ldc + n] = f2bf(v);
                else             (ch.C  + bz * cB)[m * ldc + n] = v;
            }
        }
    }
}

// ---------------------------------------------------------------------------
// Single bf16 MFMA GEMM (EPI 3 = abs-row-max -> denom; EPI 4 = bias+resid f32)
// ---------------------------------------------------------------------------
template<int BM, int EPI>
__global__ __launch_bounds__(256) void mgemm(
    const unsigned short* __restrict__ A, const unsigned short* __restrict__ Bt,
    const float* __restrict__ bias, const float* __restrict__ resid,
    float* __restrict__ C, float* __restrict__ denom,
    int K, int lda, int ldbt, int ldc)
{
    constexpr int MR = BM / 32;
    constexpr int AP = BM / 64;
    XCD_SWZ();

    __shared__ __align__(16) unsigned short As[2][BM][40];
    __shared__ __align__(16) unsigned short Bs[2][128][40];

    const int t = threadIdx.x;
    const int w = t >> 6, l = t & 63;
    const int wr = w >> 1, wc = w & 1;
    const long rowA = (long)by * BM;
    const long rowB = (long)bx * 128;

    const int lr = t >> 2;
    const int lc = (t & 3) << 3;
    const unsigned short* Ag = A  + (rowA + lr) * (long)lda  + lc;
    const unsigned short* Bg = Bt + (rowB + lr) * (long)ldbt + lc;

    const int lm = l & 15;
    const int lk = (l >> 4) * 8;

    f32x4_t acc[MR][4];
#pragma unroll
    for (int mi = 0; mi < MR; ++mi)
#pragma unroll
        for (int ni = 0; ni < 4; ++ni) acc[mi][ni] = (f32x4_t)0.0f;

    bf16x8_t ra[AP], rb[2];
#pragma unroll
    for (int p = 0; p < AP; ++p) ra[p] = *(const bf16x8_t*)(Ag + (long)p * 64 * lda);
#pragma unroll
    for (int p = 0; p < 2;  ++p) rb[p] = *(const bf16x8_t*)(Bg + (long)p * 64 * ldbt);
#pragma unroll
    for (int p = 0; p < AP; ++p) *(bf16x8_t*)&As[0][lr + p * 64][lc] = ra[p];
#pragma unroll
    for (int p = 0; p < 2;  ++p) *(bf16x8_t*)&Bs[0][lr + p * 64][lc] = rb[p];
    __syncthreads();

    const int nsteps = K >> 5;
    for (int ti = 0; ti < nsteps; ++ti) {
        const int cur = ti & 1;
        if (ti + 1 < nsteps) {
            const int kb = (ti + 1) << 5;
#pragma unroll
            for (int p = 0; p < AP; ++p) ra[p] = *(const bf16x8_t*)(Ag + (long)p * 64 * lda  + kb);
#pragma unroll
            for (int p = 0; p < 2;  ++p) rb[p] = *(const bf16x8_t*)(Bg + (long)p * 64 * ldbt + kb);
        }
        bf16x8_t af[MR], bfr[4];
#pragma unroll
        for (int mi = 0; mi < MR; ++mi)
            af[mi] = *(const bf16x8_t*)&As[cur][wr * (BM / 2) + mi * 16 + lm][lk];
#pragma unroll
        for (int ni = 0; ni < 4; ++ni)
            bfr[ni] = *(const bf16x8_t*)&Bs[cur][wc * 64 + ni * 16 + lm][lk];
#pragma unroll
        for (int mi = 0; mi < MR; ++mi)
#pragma unroll
            for (int ni = 0; ni < 4; ++ni)
                acc[mi][ni] = __builtin_amdgcn_mfma_f32_16x16x32_bf16(
                    af[mi], bfr[ni], acc[mi][ni], 0, 0, 0);
        if (ti + 1 < nsteps) {
            const int nxt = cur ^ 1;
#pragma unroll
            for (int p = 0; p < AP; ++p) *(bf16x8_t*)&As[nxt][lr + p * 64][lc] = ra[p];
#pragma unroll
            for (int p = 0; p < 2;  ++p) *(bf16x8_t*)&Bs[nxt][lr + p * 64][lc] = rb[p];
        }
        __syncthreads();
    }

    const int lr4 = (l >> 4) * 4;
    if (EPI == 3) {
        float rmax[MR][4];
#pragma unroll
        for (int mi = 0; mi < MR; ++mi)
#pragma unroll
            for (int r = 0; r < 4; ++r) {
                float m = 0.0f;
#pragma unroll
                for (int ni = 0; ni < 4; ++ni) m = fmaxf(m, fabsf(acc[mi][ni][r]));
                rmax[mi][r] = m;
            }
#pragma unroll
        for (int off = 1; off < 16; off <<= 1)
#pragma unroll
            for (int mi = 0; mi < MR; ++mi)
#pragma unroll
                for (int r = 0; r < 4; ++r)
                    rmax[mi][r] = fmaxf(rmax[mi][r], __shfl_xor(rmax[mi][r], off, 64));
        if (lm == 0) {
#pragma unroll
            for (int mi = 0; mi < MR; ++mi)
#pragma unroll
                for (int r = 0; r < 4; ++r) {
                    const long m = rowA + wr * (BM / 2) + mi * 16 + lr4 + r;
                    atomicMax((unsigned int*)&denom[m], __float_as_uint(rmax[mi][r]));
                }
        }
        return;
    }
#pragma unroll
    for (int mi = 0; mi < MR; ++mi) {
        const long m0 = rowA + wr * (BM / 2) + mi * 16 + lr4;
#pragma unroll
        for (int ni = 0; ni < 4; ++ni) {
            const long n = rowB + wc * 64 + ni * 16 + lm;
            const float bv = bias[n];
#pragma unroll
            for (int r = 0; r < 4; ++r) {
                float v = acc[mi][ni][r] + bv;
                const long m = m0 + r;
                v += resid[m * ldc + n];
                C[m * ldc + n] = v;
            }
        }
    }
}

// ---------------------------------------------------------------------------
// Transpose + f32->bf16: X (R,C) f32 -> XT (C,R) bf16. Batched via blockIdx.z.
// ---------------------------------------------------------------------------
__global__ __launch_bounds__(256) void transpose_bf(
    const float* __restrict__ X, unsigned short* __restrict__ XT, int R, int C)
{
    __shared__ float tile[64][65];
    X  += (long)blockIdx.z * R * C;
    XT += (long)blockIdx.z * R * C;
    const int t = threadIdx.x;
    const long r0 = (long)blockIdx.y * 64;
    const long c0 = (long)blockIdx.x * 64;
    const int tr = t >> 4;
    const int tc = (t & 15) << 2;
#pragma unroll
    for (int p = 0; p < 4; ++p) {
        const float4 v = *(const float4*)(X + (r0 + tr + p * 16) * C + c0 + tc);
        tile[tr + p * 16][tc + 0] = v.x;
        tile[tr + p * 16][tc + 1] = v.y;
        tile[tr + p * 16][tc + 2] = v.z;
        tile[tr + p * 16][tc + 3] = v.w;
    }
    __syncthreads();
#pragma unroll
    for (int p = 0; p < 4; ++p) {
        const int cc = tr + p * 16;
        us4_t o;
        o.x = f2bf(tile[tc + 0][cc]);
        o.y = f2bf(tile[tc + 1][cc]);
        o.z = f2bf(tile[tc + 2][cc]);
        o.w = f2bf(tile[tc + 3][cc]);
        *(us4_t*)(XT + (c0 + cc) * (long)R + r0 + tc) = o;
    }
}

// ---------------------------------------------------------------------------
// LayerNorm over D_IN per row -> bf16
// ---------------------------------------------------------------------------
__global__ __launch_bounds__(256) void layernorm_kernel(
    const float* __restrict__ x, const float* __restrict__ w,
    const float* __restrict__ b, unsigned short* __restrict__ out)
{
    __shared__ float sh[8];
    const int row = blockIdx.x, t = threadIdx.x;
    const float* xr = x + (long)row * D_IN;
    float v[8];
    float s = 0.f, ss = 0.f;
#pragma unroll
    for (int i = 0; i < 8; ++i) {
        v[i] = xr[t + 256 * i];
        s += v[i];
        ss += v[i] * v[i];
    }
#pragma unroll
    for (int off = 32; off; off >>= 1) {
        s  += __shfl_down(s, off, 64);
        ss += __shfl_down(ss, off, 64);
    }
    const int lane = t & 63, wid = t >> 6;
    if (lane == 0) { sh[wid * 2] = s; sh[wid * 2 + 1] = ss; }
    __syncthreads();
    s = 0.f; ss = 0.f;
#pragma unroll
    for (int i = 0; i < 4; ++i) { s += sh[i * 2]; ss += sh[i * 2 + 1]; }
    const float mu  = s * (1.0f / D_IN);
    const float var = ss * (1.0f / D_IN) - mu * mu;
    const float rs  = rsqrtf(var + LN_EPS);
    unsigned short* orow = out + (long)row * D_IN;
#pragma unroll
    for (int i = 0; i < 8; ++i) {
        const int d = t + 256 * i;
        orow[d] = f2bf((v[i] - mu) * rs * w[d] + b[d]);
    }
}

// ---------------------------------------------------------------------------
// Causal conv1d (K=4, left pad 3) + SiLU.  bf16 -> bf16
// ---------------------------------------------------------------------------
__global__ void conv_silu_kernel(const unsigned short* __restrict__ xl,
                                 const float* __restrict__ cw,
                                 const float* __restrict__ cb,
                                 unsigned short* __restrict__ out)
{
    const long idx = (long)blockIdx.x * blockDim.x + threadIdx.x;
    if (idx >= (long)B_ROWS * D_UP) return;
    const int d = (int)(idx & (D_UP - 1));
    const float w0 = cw[0], w1 = cw[1], w2 = cw[2], w3 = cw[3];
    float acc = cb[0] + w3 * bf2f(xl[idx]);
    if (d >= 1) acc += w2 * bf2f(xl[idx - 1]);
    if (d >= 2) acc += w1 * bf2f(xl[idx - 2]);
    if (d >= 3) acc += w0 * bf2f(xl[idx - 3]);
    out[idx] = f2bf(siluf_(acc));
}

// ---------------------------------------------------------------------------
// Stabilized exponential gating -> m_t, c_t, n_t (direct to d_out)
// ---------------------------------------------------------------------------
__global__ void gating_kernel(const float* __restrict__ it, const float* __restrict__ ft,
                              const float* __restrict__ mp, const float* __restrict__ cp,
                              const float* __restrict__ np_, const float* __restrict__ kk,
                              const float* __restrict__ vv,
                              float* __restrict__ mt, float* __restrict__ ct,
                              float* __restrict__ nt)
{
    const long idx = (long)blockIdx.x * blockDim.x + threadIdx.x;
    if (idx >= (long)B_ROWS * D_HID) return;
    const float i_t = it[idx];
    const float f_t = ft[idx] + mp[idx];
    const float m_t = fmaxf(f_t, i_t);
    const float i_g = expf(i_t - m_t);
    const float f_g = expf(f_t - m_t);
    const float kv  = kk[idx];
    ct[idx] = f_g * cp[idx] + i_g * (vv[idx] * kv);
    nt[idx] = f_g * np_[idx] + i_g * kv;
    mt[idx] = m_t;
}

// ---------------------------------------------------------------------------
// Fused: h_t = sigmoid(op)*c_t*q/denom  +  GroupNorm + skip + silu-gate
// One block (128 thr) per (row, head).
// ---------------------------------------------------------------------------
__global__ __launch_bounds__(128) void hgnorm_kernel(
    const float* __restrict__ op, const float* __restrict__ ct,
    const float* __restrict__ qb, const float* __restrict__ denom,
    const float* __restrict__ gw, const float* __restrict__ gb,
    const float* __restrict__ xskip, const float* __restrict__ xupR,
    float* __restrict__ ht, unsigned short* __restrict__ out)
{
    __shared__ float sh[4];
    const int b = blockIdx.x >> 3, h = blockIdx.x & 7;
    const int t = threadIdx.x;
    const long base = (long)b * D_HID + h * HS;
    float v[4];
    float s = 0.f, ss = 0.f;
#pragma unroll
    for (int i = 0; i < 4; ++i) {
        const long ix = base + t + 128 * i;
        const int  dg = h * HS + t + 128 * i;
        const float hv = sigmoidf_(op[ix]) * ct[ix] * qb[ix] / denom[dg];
        ht[ix] = hv;
        v[i] = hv;
        s += hv;
        ss += hv * hv;
    }
#pragma unroll
    for (int off = 32; off; off >>= 1) {
        s  += __shfl_down(s, off, 64);
        ss += __shfl_down(ss, off, 64);
    }
    if ((t & 63) == 0) { sh[(t >> 6) * 2] = s; sh[(t >> 6) * 2 + 1] = ss; }
    __syncthreads();
    s = sh[0] + sh[2];
    ss = sh[1] + sh[3];
    const float mu  = s * (1.0f / HS);
    const float var = ss * (1.0f / HS) - mu * mu;
    const float rs  = rsqrtf(var + LN_EPS);
#pragma unroll
    for (int i = 0; i < 4; ++i) {
        const int  dg = h * HS + t + 128 * i;
        const long ix = base + t + 128 * i;
        const float g = (v[i] - mu) * rs * gw[dg] + gb[dg];
        out[ix] = f2bf((g + xskip[ix]) * siluf_(xupR[ix]));
    }
}

// ---------------------------------------------------------------------------
extern "C" void kernel_launch(void* const* d_in, const int* in_sizes, int n_in,
                              void* d_out, int out_size, void* d_ws, size_t ws_size,
                              hipStream_t stream)
{
    const float* x      = (const float*)d_in[0];
    const float* c_prev = (const float*)d_in[2];
    const float* n_prev = (const float*)d_in[3];
    const float* m_prev = (const float*)d_in[4];
    const float* ln_w   = (const float*)d_in[5];
    const float* ln_b   = (const float*)d_in[6];
    const float* upL_w  = (const float*)d_in[7];
    const float* upL_b  = (const float*)d_in[8];
    const float* upR_w  = (const float*)d_in[9];
    const float* upR_b  = (const float*)d_in[10];
    const float* conv_w = (const float*)d_in[11];
    const float* conv_b = (const float*)d_in[12];
    const float* skip_w = (const float*)d_in[13];
    const float* skip_b = (const float*)d_in[14];
    const float* wq     = (const float*)d_in[15];
    const float* bq     = (const float*)d_in[16];
    const float* wk     = (const float*)d_in[17];
    const float* bk     = (const float*)d_in[18];
    const float* wv     = (const float*)d_in[19];
    const float* bv     = (const float*)d_in[20];
    const float* wi_w   = (const float*)d_in[21];
    const float* wi_b   = (const float*)d_in[22];
    const float* wf_w   = (const float*)d_in[23];
    const float* wf_b   = (const float*)d_in[24];
    const float* wo_w   = (const float*)d_in[25];
    const float* wo_b   = (const float*)d_in[26];
    const float* gn_w   = (const float*)d_in[27];
    const float* gn_b   = (const float*)d_in[28];
    const float* down_w = (const float*)d_in[29];
    const float* down_b = (const float*)d_in[30];

    float* out     = (float*)d_out;
    float* final_o = out;                       // (1024, 2048)
    float* ht      = final_o + 2097152;         // (1024, 4096)
    float* ct      = ht + 4194304;
    float* nt      = ct + 4194304;
    float* mt      = nt + 4194304;

    // d_out scratch for transposed weights (consumed before gating/hgnorm
    // write these regions; stream-serial ordering guarantees safety).
    unsigned short* WTA = (unsigned short*)ht;  // 16M bf16 el (ht+ct, 32MB)
    unsigned short* WTB = (unsigned short*)nt;  // 16M bf16 el (nt+mt, 32MB)

    // workspace (f32 element offsets); total ~= 148MB
    const long M4 = 4194304;
    float* ws    = (float*)d_ws;
    float* xupR  = ws + 0 * M4;
    float* xskip = ws + 1 * M4;
    float* qb    = ws + 2 * M4;
    float* kb    = ws + 3 * M4;
    float* vb    = ws + 4 * M4;
    float* itb   = ws + 5 * M4;
    float* ftb   = ws + 6 * M4;
    float* opb   = ws + 7 * M4;
    unsigned short* xnorm_bf = (unsigned short*)(ws + 8 * M4);                 // 2M el
    unsigned short* xupL_bf  = (unsigned short*)(ws + 8 * M4 + 1048576);       // 4M el
    unsigned short* xconv_bf = (unsigned short*)(ws + 8 * M4 + 3 * 1048576);   // 4M el
    float* denom = ws + 8 * M4 + 5 * 1048576;                                  // 4096
    unsigned short* ntT    = (unsigned short*)kb;                 // after gating
    unsigned short* qT     = (unsigned short*)(kb + 2 * 1048576); // after gating
    unsigned short* tmp_bf = (unsigned short*)vb;                 // after gating
    unsigned short* WTdown = (unsigned short*)itb;                // after gating

    const float kscale = 1.0f / sqrtf((float)HS);
    const long HS2 = (long)HS * HS;
    MGChunk cz = {};

    // 1. LayerNorm -> bf16
    layernorm_kernel<<<B_ROWS, 256, 0, stream>>>(x, ln_w, ln_b, xnorm_bf);

    // 2. upL | upR concat (K=2048, N=8192, grid 512 blocks)
    transpose_bf<<<dim3(D_UP / 64, D_IN / 64, 1), 256, 0, stream>>>(upL_w, WTA, D_IN, D_UP);
    transpose_bf<<<dim3(D_HID / 64, D_IN / 64, 1), 256, 0, stream>>>(upR_w, WTA + 8388608, D_IN, D_HID);
    {
        MGChunk a = { xnorm_bf, WTA,           upL_b, nullptr, xupL_bf, 1.0f, 5 };
        MGChunk b = { xnorm_bf, WTA + 8388608, upR_b, xupR,    nullptr, 1.0f, 0 };
        mgemm_mc<2><<<dim3(64, 8, 1), 256, 0, stream>>>(
            a, b, cz, D_IN, D_IN, D_IN, D_HID, 32, 0, 0, 0, 0);
    }

    // 3. causal conv + silu -> bf16
    conv_silu_kernel<<<(B_ROWS * D_UP) / 256, 256, 0, stream>>>(xupL_bf, conv_w, conv_b, xconv_bf);

    // 4. skip | wi concat (K=4096, N=8192, grid 512)
    transpose_bf<<<dim3(64, 64, 1), 256, 0, stream>>>(skip_w, WTA, D_UP, D_HID);
    transpose_bf<<<dim3(64, 64, 1), 256, 0, stream>>>(wi_w,   WTB, D_UP, D_HID);
    {
        MGChunk a = { xconv_bf, WTA, skip_b, xskip, nullptr, 1.0f, 0 };
        MGChunk b = { xconv_bf, WTB, wi_b,   itb,   nullptr, 1.0f, 0 };
        mgemm_mc<2><<<dim3(64, 8, 1), 256, 0, stream>>>(
            a, b, cz, D_UP, D_UP, D_UP, D_HID, 32, 0, 0, 0, 0);
    }

    // 5. wf | wo concat (per-chunk A; grid 512)
    transpose_bf<<<dim3(64, 64, 1), 256, 0, stream>>>(wf_w, WTA, D_UP, D_HID);
    transpose_bf<<<dim3(64, 64, 1), 256, 0, stream>>>(wo_w, WTB, D_UP, D_HID);
    {
        MGChunk a = { xconv_bf, WTA, wf_b, ftb, nullptr, 1.0f, 0 };
        MGChunk b = { xupL_bf,  WTB, wo_b, opb, nullptr, 1.0f, 0 };
        mgemm_mc<2><<<dim3(64, 8, 1), 256, 0, stream>>>(
            a, b, cz, D_UP, D_UP, D_UP, D_HID, 32, 0, 0, 0, 0);
    }

    // 6. q | k | v concat, head-batched (K=512, grid 768)
    transpose_bf<<<dim3(8, 8, NH), 256, 0, stream>>>(wq, WTA,           HS, HS);
    transpose_bf<<<dim3(8, 8, NH), 256, 0, stream>>>(wk, WTA + 2097152, HS, HS);
    transpose_bf<<<dim3(8, 8, NH), 256, 0, stream>>>(wv, WTA + 4194304, HS, HS);
    {
        MGChunk a = { xconv_bf, WTA,           bq, qb, nullptr, 1.0f,   0 };
        MGChunk b = { xconv_bf, WTA + 2097152, bk, kb, nullptr, kscale, 0 };
        MGChunk c = { xupL_bf,  WTA + 4194304, bv, vb, nullptr, 1.0f,   0 };
        mgemm_mc<3><<<dim3(12, 8, NH), 256, 0, stream>>>(
            a, b, c, HS, D_UP, HS, D_HID, 4, HS, HS2, HS, HS);
    }

    // 7. gating -> m_t, c_t, n_t (overwrites WT scratch in d_out; all consumed)
    gating_kernel<<<(B_ROWS * D_HID) / 256, 256, 0, stream>>>(
        itb, ftb, m_prev, c_prev, n_prev, kb, vb, mt, ct, nt);

    // 8. denom = rowwise max |n_t^T q|  (grid 1024)
    transpose_bf<<<dim3(64, 16, 1), 256, 0, stream>>>(nt, ntT, B_ROWS, D_HID);
    transpose_bf<<<dim3(64, 16, 1), 256, 0, stream>>>(qb, qT,  B_ROWS, D_HID);
    hipMemsetAsync(denom, 0, D_HID * sizeof(float), stream);
    mgemm<128, 3><<<dim3(32, 32, 1), 256, 0, stream>>>(
        ntT, qT, nullptr, nullptr, nullptr, denom, B_ROWS, B_ROWS, B_ROWS, 0);

    // 9. down-weight transpose (into dead itb region)
    transpose_bf<<<dim3(D_IN / 64, D_HID / 64, 1), 256, 0, stream>>>(down_w, WTdown, D_HID, D_IN);

    // 10. fused h_t + GroupNorm + skip + silu-gate
    hgnorm_kernel<<<B_ROWS * NH, 128, 0, stream>>>(
        opb, ct, qb, denom, gn_w, gn_b, xskip, xupR, ht, tmp_bf);

    // 11. down-projection + residual -> final (grid 256)
    mgemm<64, 4><<<dim3(D_IN / 128, B_ROWS / 64, 1), 256, 0, stream>>>(
        tmp_bf, WTdown, down_b, x, final_o, nullptr, D_HID, D_HID, D_HID, D_IN);
}